// Round 4
// baseline (158.141 us; speedup 1.0000x reference)
//
#include <hip/hip_runtime.h>
#include <stdint.h>

#define DIMS   1000
#define NLEV   10
#define NPIX   784
#define NBATCH 256
#define NCLS   10
#define WPD    32        // u32 words per dim-row (32*32 = 1024 >= 1000)
#define FLAG_IDX 65536   // u32 index into ws (byte offset 256 KiB, clear of 100 KiB pack area)

// full adder on bit-planes: sum/carry of a+b+cin (5 ops)
__device__ __forceinline__ void fa(uint32_t a, uint32_t b, uint32_t cin,
                                   uint32_t& s, uint32_t& c) {
    uint32_t t = a ^ b;
    s = t ^ cin;
    c = (a & b) | (t & cin);
}

// ---------------------------------------------------------------------------
// Single fused kernel. One block per batch element, 512 threads, all 256
// blocks provably co-resident (8 waves/block, capacity 4 blocks/CU).
// Phase A: ballot-pack position rows into ws (3 rows/block +16 extra),
//          ballot-pack value_table into LDS, compute level indices.
// Phase B: device-scope arrival counter in ws (release fence -> add -> spin
//          -> acquire fence) — cross-XCD visibility per G16.
// Phase C: bit-sliced CSA popcount of mismatch bits, bitwise threshold,
//          tiny logit GEMV (identical to verified R3 code).
// ---------------------------------------------------------------------------
__global__ __launch_bounds__(512) void hdc_fused(
        const float* __restrict__ x, const float* __restrict__ position,
        const float* __restrict__ vtab, const float* __restrict__ W,
        uint32_t* __restrict__ ws, float* __restrict__ out) {
    __shared__ uint32_t s_idx[NPIX];             // 3136 B
    __shared__ uint32_t s_vt[NLEV * WPD];        // 1280 B
    __shared__ uint32_t s_cnt1[32 * 8 * 7];      // 7168 B
    __shared__ uint32_t s_cnt2[32 * 4 * 8];      // 4096 B
    __shared__ uint32_t s_cnt3[32 * 2 * 9];      // 2304 B
    __shared__ uint32_t s_enc[32];               //  128 B
    __shared__ float    s_red[8][NCLS];          //  320 B

    const int b    = blockIdx.x;
    const int t    = threadIdx.x;
    const int lane = t & 63;
    const int wv   = t >> 6;

    // ---- Phase A1: pack position rows (row = b + 256*wv), coalesced + ballot
    {
        int row = b + 256 * wv;
        if (row < NPIX) {
            const float* src = position + (size_t)row * DIMS;
            uint64_t* ws64 = (uint64_t*)ws;
            #pragma unroll
            for (int k = 0; k < 16; ++k) {
                int d = k * 64 + lane;
                float v = (d < DIMS) ? src[d] : 0.f;   // pad bits -> 0
                uint64_t m = __ballot(v > 0.f);
                if (lane == 0) ws64[(size_t)row * 16 + k] = m;
            }
        }
    }
    // ---- Phase A2: pack value_table straight into LDS (2 levels per wave)
    #pragma unroll
    for (int e = 0; e < 2; ++e) {
        int lev = 2 * wv + e;
        if (lev < NLEV) {
            const float* src = vtab + (size_t)lev * DIMS;
            #pragma unroll
            for (int k = 0; k < 16; ++k) {
                int d = k * 64 + lane;
                float v = (d < DIMS) ? src[d] : 0.f;
                uint64_t m = __ballot(v > 0.f);
                if (lane == 0) {
                    s_vt[lev * WPD + 2 * k]     = (uint32_t)m;
                    s_vt[lev * WPD + 2 * k + 1] = (uint32_t)(m >> 32);
                }
            }
        }
    }
    // ---- Phase A3: per-pixel level index: idx = clip(rint(x*9), 0, 9)
    for (int p = t; p < NPIX; p += 512) {
        float v = x[b * NPIX + p] * 9.0f;
        int l = (int)rintf(v);                   // half-even, matches jnp.round
        l = l < 0 ? 0 : (l > 9 ? 9 : l);
        s_idx[p] = (uint32_t)(l * WPD);          // pre-scaled row offset
    }

    // ---- Phase B: device-wide arrival handshake (counter lives in ws)
    __threadfence();            // release: make this block's pack stores visible
    __syncthreads();
    if (t == 0) {
        uint32_t* flag = ws + FLAG_IDX;
        // reset poison (0xAA fill) / previous-call leftover exactly once;
        // value can never revisit these states mid-protocol (max 256 adds).
        atomicCAS(flag, 0xAAAAAAAAu, 0u);
        atomicCAS(flag, (uint32_t)NBATCH, 0u);
        atomicAdd(flag, 1u);
        while (atomicAdd(flag, 0u) < (uint32_t)NBATCH)
            __builtin_amdgcn_s_sleep(2);
    }
    __syncthreads();
    __threadfence();            // acquire: invalidate stale L1/L2 lines

    // ---- Phase C: CSA popcount of mismatch bits (pos ^ vt[idx])
    const int w = t & 31;
    const int g = t >> 5;
    uint32_t p0 = 0, p1 = 0, p2 = 0, p3 = 0, p4 = 0, p5 = 0;

    for (int c = 0; c < 6; ++c) {
        uint32_t idxv[8], posv[8], xv[8];
        #pragma unroll
        for (int j = 0; j < 8; ++j)
            idxv[j] = s_idx[g + 128 * c + 16 * j];
        #pragma unroll
        for (int j = 0; j < 8; ++j)
            posv[j] = ws[(g + 128 * c + 16 * j) * WPD + w];   // global, L2
        #pragma unroll
        for (int j = 0; j < 8; ++j)
            xv[j] = posv[j] ^ s_vt[idxv[j] + w];              // mismatch bits
        uint32_t sa, ca, sb, cb, sc, cc, cd, se, ce, cf, cg;
        fa(xv[0], xv[1], xv[2], sa, ca);
        fa(xv[3], xv[4], xv[5], sb, cb);
        fa(xv[6], xv[7], p0,   sc, cc);
        fa(sa, sb, sc, p0, cd);          // new ones plane
        fa(ca, cb, cc, se, ce);
        fa(se, cd, p1, p1, cf);          // new twos plane
        fa(ce, cf, p2, p2, cg);          // new fours plane
        uint32_t tmp = p3 & cg; p3 ^= cg;
        uint32_t tm2 = p4 & tmp; p4 ^= tmp;
        p5 ^= tm2;
    }
    {   // tail pixel: pl = g + 768
        uint32_t xb = ws[(g + 768) * WPD + w] ^ s_vt[s_idx[g + 768] + w];
        uint32_t c = xb, tmp;
        tmp = p0 & c; p0 ^= c; c = tmp;
        tmp = p1 & c; p1 ^= c; c = tmp;
        tmp = p2 & c; p2 ^= c; c = tmp;
        tmp = p3 & c; p3 ^= c; c = tmp;
        tmp = p4 & c; p4 ^= c; c = tmp;
        p5 ^= c;
    }

    // ---- merge the wave's two groups via shuffle (6+6 -> 7 planes)
    {
        uint32_t q0 = __shfl_down(p0, 32), q1 = __shfl_down(p1, 32),
                 q2 = __shfl_down(p2, 32), q3 = __shfl_down(p3, 32),
                 q4 = __shfl_down(p4, 32), q5 = __shfl_down(p5, 32);
        uint32_t r0, r1, r2, r3, r4, r5, r6, c, tt;
        c  = p0 & q0; r0 = p0 ^ q0;
        tt = p1 ^ q1; r1 = tt ^ c; c = (p1 & q1) | (tt & c);
        tt = p2 ^ q2; r2 = tt ^ c; c = (p2 & q2) | (tt & c);
        tt = p3 ^ q3; r3 = tt ^ c; c = (p3 & q3) | (tt & c);
        tt = p4 ^ q4; r4 = tt ^ c; c = (p4 & q4) | (tt & c);
        tt = p5 ^ q5; r5 = tt ^ c; c = (p5 & q5) | (tt & c);
        r6 = c;
        const int wid = t >> 6;
        if ((t & 63) < 32) {
            int base = (w * 8 + wid) * 7;
            s_cnt1[base + 0] = r0; s_cnt1[base + 1] = r1; s_cnt1[base + 2] = r2;
            s_cnt1[base + 3] = r3; s_cnt1[base + 4] = r4; s_cnt1[base + 5] = r5;
            s_cnt1[base + 6] = r6;
        }
    }
    __syncthreads();

    // ---- tree round 2: 8 -> 4 groups (7 -> 8 planes)
    if (t < 128) {
        int w2 = t & 31, j = t >> 5;
        int ba = (w2 * 8 + 2 * j) * 7, bb = (w2 * 8 + 2 * j + 1) * 7;
        uint32_t c = 0, tt;
        int bo = (w2 * 4 + j) * 8;
        #pragma unroll
        for (int i = 0; i < 7; ++i) {
            uint32_t a = s_cnt1[ba + i], bv = s_cnt1[bb + i];
            tt = a ^ bv; s_cnt2[bo + i] = tt ^ c; c = (a & bv) | (tt & c);
        }
        s_cnt2[bo + 7] = c;
    }
    __syncthreads();

    // ---- tree round 3: 4 -> 2 groups (8 -> 9 planes)
    if (t < 64) {
        int w2 = t & 31, j = t >> 5;
        int ba = (w2 * 4 + 2 * j) * 8, bb = (w2 * 4 + 2 * j + 1) * 8;
        uint32_t c = 0, tt;
        int bo = (w2 * 2 + j) * 9;
        #pragma unroll
        for (int i = 0; i < 8; ++i) {
            uint32_t a = s_cnt2[ba + i], bv = s_cnt2[bb + i];
            tt = a ^ bv; s_cnt3[bo + i] = tt ^ c; c = (a & bv) | (tt & c);
        }
        s_cnt3[bo + 8] = c;
    }
    __syncthreads();

    // ---- final merge + bitwise threshold: enc = +1 iff mismatches <= 391
    // carry-out of (m + 632) over 10 bits == (m >= 392); enc = ~carry
    if (t < 32) {
        int ba = (t * 2) * 9, bb = (t * 2 + 1) * 9;
        uint32_t cnt[10];
        uint32_t c = 0, tt;
        #pragma unroll
        for (int i = 0; i < 9; ++i) {
            uint32_t a = s_cnt3[ba + i], bv = s_cnt3[bb + i];
            tt = a ^ bv; cnt[i] = tt ^ c; c = (a & bv) | (tt & c);
        }
        cnt[9] = c;
        // 632 = 0b1001111000
        uint32_t cy;
        cy = cnt[3];
        cy = cnt[4] | cy;
        cy = cnt[5] | cy;
        cy = cnt[6] | cy;
        cy = cnt[7] & cy;
        cy = cnt[8] & cy;
        cy = cnt[9] | cy;
        s_enc[t] = ~cy;                  // enc bit = 1 -> +1
    }
    __syncthreads();

    // ---- logits: 500 threads x 2 dims, +-W accumulate, shuffle reduce
    float partial[NCLS];
    #pragma unroll
    for (int cc = 0; cc < NCLS; ++cc) partial[cc] = 0.f;

    if (t < 500) {
        int d0 = 2 * t;
        uint32_t ew = s_enc[d0 >> 5];
        float e0 = ((ew >> (d0 & 31)) & 1u) ? 1.0f : -1.0f;
        float e1 = ((ew >> ((d0 + 1) & 31)) & 1u) ? 1.0f : -1.0f;
        #pragma unroll
        for (int cc = 0; cc < NCLS; ++cc) {
            const float2* wvp = (const float2*)(W + cc * DIMS + d0);
            float2 wl = *wvp;
            partial[cc] = e0 * wl.x + e1 * wl.y;
        }
    }
    #pragma unroll
    for (int cc = 0; cc < NCLS; ++cc) {
        #pragma unroll
        for (int off = 32; off > 0; off >>= 1)
            partial[cc] += __shfl_down(partial[cc], off);
    }
    const int wid = t >> 6;
    if (lane == 0) {
        #pragma unroll
        for (int cc = 0; cc < NCLS; ++cc) s_red[wid][cc] = partial[cc];
    }
    __syncthreads();
    if (t < NCLS) {
        float acc = 0.f;
        #pragma unroll
        for (int v = 0; v < 8; ++v) acc += s_red[v][t];
        out[b * NCLS + t] = acc;
    }
}

extern "C" void kernel_launch(void* const* d_in, const int* in_sizes, int n_in,
                              void* d_out, int out_size, void* d_ws, size_t ws_size,
                              hipStream_t stream) {
    const float* x        = (const float*)d_in[0];  // [256,28,28]
    const float* position = (const float*)d_in[1];  // [784,1000]
    const float* vtab     = (const float*)d_in[2];  // [10,1000]
    const float* W        = (const float*)d_in[3];  // [10,1000]
    float* out            = (float*)d_out;          // [256,10]

    hdc_fused<<<NBATCH, 512, 0, stream>>>(x, position, vtab, W,
                                          (uint32_t*)d_ws, out);
}

// Round 5
// 74.059 us; speedup vs baseline: 2.1353x; 2.1353x over previous
//
#include <hip/hip_runtime.h>
#include <stdint.h>

#define DIMS   1000
#define NLEV   10
#define NPIX   784
#define NBATCH 256
#define NCLS   10
#define WPD    32      // u32 words per dim-row (32*32 = 1024 >= 1000)

// ---------------------------------------------------------------------------
// Kernel 1: ballot-pack sign bits. One wave per row; 64 lanes load 64
// consecutive floats (coalesced), __ballot forms 64 bits -> one u64 store.
// Rows 0..783 = position, 784..793 = value_table (contiguous in ws).
// ---------------------------------------------------------------------------
__global__ __launch_bounds__(256) void pack_ballot(const float* __restrict__ position,
                                                   const float* __restrict__ value_table,
                                                   uint64_t* __restrict__ ws64) {
    const int t    = threadIdx.x;
    const int lane = t & 63;
    const int wv   = (blockIdx.x * 256 + t) >> 6;
    const int nw   = (gridDim.x * 256) >> 6;
    for (int r = wv; r < NPIX + NLEV; r += nw) {
        const float* src = (r < NPIX) ? (position + (size_t)r * DIMS)
                                      : (value_table + (size_t)(r - NPIX) * DIMS);
        #pragma unroll
        for (int k = 0; k < 16; ++k) {           // 16*64 = 1024 >= 1000
            int d = k * 64 + lane;
            float v = (d < DIMS) ? src[d] : 0.f; // pad bits -> 0 (harmless)
            uint64_t m = __ballot(v > 0.f);
            if (lane == 0) ws64[(size_t)r * 16 + k] = m;
        }
    }
}

// full adder on bit-planes: sum/carry of a+b+cin (5 ops)
__device__ __forceinline__ void fa(uint32_t a, uint32_t b, uint32_t cin,
                                   uint32_t& s, uint32_t& c) {
    uint32_t t = a ^ b;
    s = t ^ cin;
    c = (a & b) | (t & cin);
}

// ---------------------------------------------------------------------------
// Kernel 2: one block per batch element, 1024 threads (16 waves/CU).
// lane role: w = t&31 (dim word), g = t>>5 (pixel group, 32 groups).
// Group g covers pixels g+32k (k=0..23) plus tail 768+g for g<16 (24/25 pix).
// CSA-count mismatch bits (pos^vt) into 5 bit-planes, wave-merge to 6,
// LDS tree 16->8->4->2->1 groups, bitwise threshold, 1000-thread GEMV.
// ---------------------------------------------------------------------------
__global__ __launch_bounds__(1024) void hdc_main(const float* __restrict__ x,
                                                 const float* __restrict__ W,
                                                 const uint32_t* __restrict__ ws_bits,
                                                 float* __restrict__ out) {
    __shared__ uint32_t s_idx[NPIX];             //  3136 B
    __shared__ uint32_t s_vt[NLEV * WPD];        //  1280 B
    __shared__ uint32_t s_cnt1[32 * 16 * 6];     // 12288 B (16 merged groups x 6 planes)
    __shared__ uint32_t s_cnt2[32 * 8 * 7];      //  7168 B
    __shared__ uint32_t s_cnt3[32 * 4 * 8];      //  4096 B
    __shared__ uint32_t s_cnt4[32 * 2 * 9];      //  2304 B
    __shared__ uint32_t s_enc[32];               //   128 B
    __shared__ float    s_red[16][NCLS];         //   640 B

    const int b = blockIdx.x;
    const int t = threadIdx.x;

    // --- per-pixel level index: idx = clip(rint(x*9), 0, 9)
    if (t < NPIX) {
        float v = x[b * NPIX + t] * 9.0f;
        int l = (int)rintf(v);                   // half-even, matches jnp.round
        l = l < 0 ? 0 : (l > 9 ? 9 : l);
        s_idx[t] = (uint32_t)(l * WPD);          // pre-scaled row offset
    }
    if (t < NLEV * WPD) s_vt[t] = ws_bits[NPIX * WPD + t];
    __syncthreads();

    const int w = t & 31;
    const int g = t >> 5;

    uint32_t p0 = 0, p1 = 0, p2 = 0, p3 = 0, p4 = 0;

    // 3 chunks of 8 pixels: p = g + 32*(8c + j)
    for (int c = 0; c < 3; ++c) {
        uint32_t idxv[8], posv[8], xv[8];
        #pragma unroll
        for (int j = 0; j < 8; ++j)
            idxv[j] = s_idx[g + 256 * c + 32 * j];
        #pragma unroll
        for (int j = 0; j < 8; ++j)
            posv[j] = ws_bits[(g + 256 * c + 32 * j) * WPD + w];   // global, L2
        #pragma unroll
        for (int j = 0; j < 8; ++j)
            xv[j] = posv[j] ^ s_vt[idxv[j] + w];                   // mismatch bits
        uint32_t sa, ca, sb, cb, sc, cc, cd, se, ce, cf, cg;
        fa(xv[0], xv[1], xv[2], sa, ca);
        fa(xv[3], xv[4], xv[5], sb, cb);
        fa(xv[6], xv[7], p0,   sc, cc);
        fa(sa, sb, sc, p0, cd);          // ones plane
        fa(ca, cb, cc, se, ce);
        fa(se, cd, p1, p1, cf);          // twos plane
        fa(ce, cf, p2, p2, cg);          // fours plane
        uint32_t tmp = p3 & cg; p3 ^= cg;          // weight-8 ripple
        p4 ^= tmp;
    }
    if (g < 16) {   // tail pixel p = 768 + g
        uint32_t xb = ws_bits[(768 + g) * WPD + w] ^ s_vt[s_idx[768 + g] + w];
        uint32_t c = xb, tmp;
        tmp = p0 & c; p0 ^= c; c = tmp;
        tmp = p1 & c; p1 ^= c; c = tmp;
        tmp = p2 & c; p2 ^= c; c = tmp;
        tmp = p3 & c; p3 ^= c; c = tmp;
        p4 ^= c;
    }

    // --- merge the wave's two groups via shuffle (5+5 -> 6 planes)
    {
        uint32_t q0 = __shfl_down(p0, 32), q1 = __shfl_down(p1, 32),
                 q2 = __shfl_down(p2, 32), q3 = __shfl_down(p3, 32),
                 q4 = __shfl_down(p4, 32);
        uint32_t r0, r1, r2, r3, r4, r5, c, tt;
        c  = p0 & q0; r0 = p0 ^ q0;
        tt = p1 ^ q1; r1 = tt ^ c; c = (p1 & q1) | (tt & c);
        tt = p2 ^ q2; r2 = tt ^ c; c = (p2 & q2) | (tt & c);
        tt = p3 ^ q3; r3 = tt ^ c; c = (p3 & q3) | (tt & c);
        tt = p4 ^ q4; r4 = tt ^ c; c = (p4 & q4) | (tt & c);
        r5 = c;
        const int wv = t >> 6;               // merged group 0..15
        if ((t & 63) < 32) {
            int base = (w * 16 + wv) * 6;
            s_cnt1[base + 0] = r0; s_cnt1[base + 1] = r1; s_cnt1[base + 2] = r2;
            s_cnt1[base + 3] = r3; s_cnt1[base + 4] = r4; s_cnt1[base + 5] = r5;
        }
    }
    __syncthreads();

    // --- tree round 2: 16 -> 8 groups (6 -> 7 planes), 256 threads
    if (t < 256) {
        int w2 = t & 31, j = t >> 5;
        int ba = (w2 * 16 + 2 * j) * 6, bb = (w2 * 16 + 2 * j + 1) * 6;
        uint32_t c = 0, tt;
        int bo = (w2 * 8 + j) * 7;
        #pragma unroll
        for (int i = 0; i < 6; ++i) {
            uint32_t a = s_cnt1[ba + i], bv = s_cnt1[bb + i];
            tt = a ^ bv; s_cnt2[bo + i] = tt ^ c; c = (a & bv) | (tt & c);
        }
        s_cnt2[bo + 6] = c;
    }
    __syncthreads();

    // --- tree round 3: 8 -> 4 groups (7 -> 8 planes), 128 threads
    if (t < 128) {
        int w2 = t & 31, j = t >> 5;
        int ba = (w2 * 8 + 2 * j) * 7, bb = (w2 * 8 + 2 * j + 1) * 7;
        uint32_t c = 0, tt;
        int bo = (w2 * 4 + j) * 8;
        #pragma unroll
        for (int i = 0; i < 7; ++i) {
            uint32_t a = s_cnt2[ba + i], bv = s_cnt2[bb + i];
            tt = a ^ bv; s_cnt3[bo + i] = tt ^ c; c = (a & bv) | (tt & c);
        }
        s_cnt3[bo + 7] = c;
    }
    __syncthreads();

    // --- tree round 4: 4 -> 2 groups (8 -> 9 planes), 64 threads
    if (t < 64) {
        int w2 = t & 31, j = t >> 5;
        int ba = (w2 * 4 + 2 * j) * 8, bb = (w2 * 4 + 2 * j + 1) * 8;
        uint32_t c = 0, tt;
        int bo = (w2 * 2 + j) * 9;
        #pragma unroll
        for (int i = 0; i < 8; ++i) {
            uint32_t a = s_cnt3[ba + i], bv = s_cnt3[bb + i];
            tt = a ^ bv; s_cnt4[bo + i] = tt ^ c; c = (a & bv) | (tt & c);
        }
        s_cnt4[bo + 8] = c;
    }
    __syncthreads();

    // --- final merge + bitwise threshold: enc = +1 iff mismatches <= 391
    // carry-out of (m + 632) over 10 bits == (m >= 392); enc = ~carry
    if (t < 32) {
        int ba = (t * 2) * 9, bb = (t * 2 + 1) * 9;
        uint32_t cnt[10];
        uint32_t c = 0, tt;
        #pragma unroll
        for (int i = 0; i < 9; ++i) {
            uint32_t a = s_cnt4[ba + i], bv = s_cnt4[bb + i];
            tt = a ^ bv; cnt[i] = tt ^ c; c = (a & bv) | (tt & c);
        }
        cnt[9] = c;
        // 632 = 0b1001111000 : bits 3,4,5,6,9 set
        uint32_t cy;
        cy = cnt[3];
        cy = cnt[4] | cy;
        cy = cnt[5] | cy;
        cy = cnt[6] | cy;
        cy = cnt[7] & cy;
        cy = cnt[8] & cy;
        cy = cnt[9] | cy;
        s_enc[t] = ~cy;                  // enc bit = 1 -> +1
    }
    __syncthreads();

    // --- logits: 1000 threads x 1 dim, +-W accumulate, shuffle reduce
    float partial[NCLS];
    #pragma unroll
    for (int cc = 0; cc < NCLS; ++cc) partial[cc] = 0.f;

    if (t < DIMS) {
        uint32_t ew = s_enc[t >> 5];
        float e = ((ew >> (t & 31)) & 1u) ? 1.0f : -1.0f;
        #pragma unroll
        for (int cc = 0; cc < NCLS; ++cc)
            partial[cc] = e * W[cc * DIMS + t];
    }
    #pragma unroll
    for (int cc = 0; cc < NCLS; ++cc) {
        #pragma unroll
        for (int off = 32; off > 0; off >>= 1)
            partial[cc] += __shfl_down(partial[cc], off);
    }
    const int lane = t & 63, wv = t >> 6;
    if (lane == 0) {
        #pragma unroll
        for (int cc = 0; cc < NCLS; ++cc) s_red[wv][cc] = partial[cc];
    }
    __syncthreads();
    if (t < NCLS) {
        float acc = 0.f;
        #pragma unroll
        for (int v = 0; v < 16; ++v) acc += s_red[v][t];
        out[b * NCLS + t] = acc;
    }
}

extern "C" void kernel_launch(void* const* d_in, const int* in_sizes, int n_in,
                              void* d_out, int out_size, void* d_ws, size_t ws_size,
                              hipStream_t stream) {
    const float* x        = (const float*)d_in[0];  // [256,28,28]
    const float* position = (const float*)d_in[1];  // [784,1000]
    const float* vtab     = (const float*)d_in[2];  // [10,1000]
    const float* W        = (const float*)d_in[3];  // [10,1000]
    float* out            = (float*)d_out;          // [256,10]

    pack_ballot<<<200, 256, 0, stream>>>(position, vtab, (uint64_t*)d_ws);
    hdc_main<<<NBATCH, 1024, 0, stream>>>(x, W, (const uint32_t*)d_ws, out);
}

// Round 6
// 72.319 us; speedup vs baseline: 2.1867x; 1.0241x over previous
//
#include <hip/hip_runtime.h>
#include <stdint.h>

#define DIMS   1000
#define NLEV   10
#define NPIX   784
#define NBATCH 256
#define NCLS   10
#define WPD    32      // u32 words per dim-row (32*32 = 1024 >= 1000)

// ---------------------------------------------------------------------------
// Kernel 1: ballot-pack sign bits. One wave per row; 64 lanes load 64
// consecutive floats (coalesced), __ballot forms 64 bits -> one u64 store.
// Rows 0..783 = position, 784..793 = value_table (contiguous in ws).
// ---------------------------------------------------------------------------
__global__ __launch_bounds__(256) void pack_ballot(const float* __restrict__ position,
                                                   const float* __restrict__ value_table,
                                                   uint64_t* __restrict__ ws64) {
    const int t    = threadIdx.x;
    const int lane = t & 63;
    const int wv   = (blockIdx.x * 256 + t) >> 6;
    const int nw   = (gridDim.x * 256) >> 6;
    for (int r = wv; r < NPIX + NLEV; r += nw) {
        const float* src = (r < NPIX) ? (position + (size_t)r * DIMS)
                                      : (value_table + (size_t)(r - NPIX) * DIMS);
        #pragma unroll
        for (int k = 0; k < 16; ++k) {           // 16*64 = 1024 >= 1000
            int d = k * 64 + lane;
            float v = (d < DIMS) ? src[d] : 0.f; // pad bits -> 0 (harmless)
            uint64_t m = __ballot(v > 0.f);
            if (lane == 0) ws64[(size_t)r * 16 + k] = m;
        }
    }
}

// full adder on bit-planes: sum/carry of a+b+cin (5 ops)
__device__ __forceinline__ void fa(uint32_t a, uint32_t b, uint32_t cin,
                                   uint32_t& s, uint32_t& c) {
    uint32_t t = a ^ b;
    s = t ^ cin;
    c = (a & b) | (t & cin);
}

// ---------------------------------------------------------------------------
// Kernel 2: one block per batch element, 512 threads (8 waves/CU — measured
// best config, R3 = 72.2 us; 1024-thread variant regressed to 74.1).
// lane role: w = t&31 (dim word), g = t>>5 (pixel group, 16 groups x 49 pix).
// Count per-dim MISMATCH bits (pos^vt) with a CSA tree into 6 bit-planes,
// merge groups via bit-sliced adds, threshold bitwise, then tiny logit GEMV.
// ---------------------------------------------------------------------------
__global__ __launch_bounds__(512) void hdc_main(const float* __restrict__ x,
                                                const float* __restrict__ W,
                                                const uint32_t* __restrict__ ws_bits,
                                                float* __restrict__ out) {
    __shared__ uint32_t s_idx[NPIX];             // 3136 B
    __shared__ uint32_t s_vt[NLEV * WPD];        // 1280 B
    __shared__ uint32_t s_cnt1[32 * 8 * 7];      // 7168 B (8 merged groups x 7 planes)
    __shared__ uint32_t s_cnt2[32 * 4 * 8];      // 4096 B
    __shared__ uint32_t s_cnt3[32 * 2 * 9];      // 2304 B
    __shared__ uint32_t s_cnt4_enc[32];          //  128 B (enc bits per word)
    __shared__ float    s_red[8][NCLS];          //  320 B

    const int b = blockIdx.x;
    const int t = threadIdx.x;

    // --- per-pixel level index: idx = clip(rint(x*9), 0, 9)
    for (int p = t; p < NPIX; p += 512) {
        float v = x[b * NPIX + p] * 9.0f;
        int l = (int)rintf(v);                   // half-even, matches jnp.round
        l = l < 0 ? 0 : (l > 9 ? 9 : l);
        s_idx[p] = (uint32_t)(l * WPD);          // pre-scaled row offset
    }
    if (t < NLEV * WPD) s_vt[t] = ws_bits[NPIX * WPD + t];
    __syncthreads();

    const int w = t & 31;
    const int g = t >> 5;

    uint32_t p0 = 0, p1 = 0, p2 = 0, p3 = 0, p4 = 0, p5 = 0;

    // pixels for group g: pl = g + 16*k, k = 0..48  (49 pixels, 6 chunks of 8 + 1)
    for (int c = 0; c < 6; ++c) {
        uint32_t idxv[8], posv[8], xv[8];
        #pragma unroll
        for (int j = 0; j < 8; ++j)
            idxv[j] = s_idx[g + 128 * c + 16 * j];
        #pragma unroll
        for (int j = 0; j < 8; ++j)
            posv[j] = ws_bits[(g + 128 * c + 16 * j) * WPD + w];   // global, L2
        #pragma unroll
        for (int j = 0; j < 8; ++j)
            xv[j] = posv[j] ^ s_vt[idxv[j] + w];                   // mismatch bits
        // CSA tree: 8 inputs -> planes
        uint32_t sa, ca, sb, cb, sc, cc, cd, se, ce, cf, cg;
        fa(xv[0], xv[1], xv[2], sa, ca);
        fa(xv[3], xv[4], xv[5], sb, cb);
        fa(xv[6], xv[7], p0,   sc, cc);
        fa(sa, sb, sc, p0, cd);          // new ones plane
        fa(ca, cb, cc, se, ce);
        fa(se, cd, p1, p1, cf);          // new twos plane
        fa(ce, cf, p2, p2, cg);          // new fours plane
        uint32_t tmp = p3 & cg; p3 ^= cg;          // ripple weight-8 carry
        uint32_t tm2 = p4 & tmp; p4 ^= tmp;
        p5 ^= tm2;
    }
    {   // tail pixel: pl = g + 768
        uint32_t xb = ws_bits[(g + 768) * WPD + w] ^ s_vt[s_idx[g + 768] + w];
        uint32_t c = xb, tmp;
        tmp = p0 & c; p0 ^= c; c = tmp;
        tmp = p1 & c; p1 ^= c; c = tmp;
        tmp = p2 & c; p2 ^= c; c = tmp;
        tmp = p3 & c; p3 ^= c; c = tmp;
        tmp = p4 & c; p4 ^= c; c = tmp;
        p5 ^= c;
    }

    // --- merge the wave's two groups via shuffle: lanes 0..31 get g, 32..63 hold g+1
    {
        uint32_t q0 = __shfl_down(p0, 32), q1 = __shfl_down(p1, 32),
                 q2 = __shfl_down(p2, 32), q3 = __shfl_down(p3, 32),
                 q4 = __shfl_down(p4, 32), q5 = __shfl_down(p5, 32);
        // 6-plane + 6-plane -> 7-plane bit-sliced add (lanes<32 meaningful)
        uint32_t r0, r1, r2, r3, r4, r5, r6, c, tt;
        c  = p0 & q0; r0 = p0 ^ q0;
        tt = p1 ^ q1; r1 = tt ^ c; c = (p1 & q1) | (tt & c);
        tt = p2 ^ q2; r2 = tt ^ c; c = (p2 & q2) | (tt & c);
        tt = p3 ^ q3; r3 = tt ^ c; c = (p3 & q3) | (tt & c);
        tt = p4 ^ q4; r4 = tt ^ c; c = (p4 & q4) | (tt & c);
        tt = p5 ^ q5; r5 = tt ^ c; c = (p5 & q5) | (tt & c);
        r6 = c;
        const int wid = t >> 6;                 // merged group 0..7
        if ((t & 63) < 32) {
            int base = (w * 8 + wid) * 7;
            s_cnt1[base + 0] = r0; s_cnt1[base + 1] = r1; s_cnt1[base + 2] = r2;
            s_cnt1[base + 3] = r3; s_cnt1[base + 4] = r4; s_cnt1[base + 5] = r5;
            s_cnt1[base + 6] = r6;
        }
    }
    __syncthreads();

    // --- tree round 2: 8 -> 4 groups (7 -> 8 planes), 128 threads
    if (t < 128) {
        int w2 = t & 31, j = t >> 5;
        int ba = (w2 * 8 + 2 * j) * 7, bb = (w2 * 8 + 2 * j + 1) * 7;
        uint32_t c = 0, tt;
        int bo = (w2 * 4 + j) * 8;
        #pragma unroll
        for (int i = 0; i < 7; ++i) {
            uint32_t a = s_cnt1[ba + i], bv = s_cnt1[bb + i];
            tt = a ^ bv; s_cnt2[bo + i] = tt ^ c; c = (a & bv) | (tt & c);
        }
        s_cnt2[bo + 7] = c;
    }
    __syncthreads();

    // --- tree round 3: 4 -> 2 groups (8 -> 9 planes), 64 threads
    if (t < 64) {
        int w2 = t & 31, j = t >> 5;
        int ba = (w2 * 4 + 2 * j) * 8, bb = (w2 * 4 + 2 * j + 1) * 8;
        uint32_t c = 0, tt;
        int bo = (w2 * 2 + j) * 9;
        #pragma unroll
        for (int i = 0; i < 8; ++i) {
            uint32_t a = s_cnt2[ba + i], bv = s_cnt2[bb + i];
            tt = a ^ bv; s_cnt3[bo + i] = tt ^ c; c = (a & bv) | (tt & c);
        }
        s_cnt3[bo + 8] = c;
    }
    __syncthreads();

    // --- final merge + bitwise threshold, 32 threads
    // m[d] = mismatch count; enc = +1 iff matches > 392 iff m <= 391
    // carry-out of (m + 632) over 10 bits == (m >= 392); enc = ~carry
    if (t < 32) {
        int ba = (t * 2) * 9, bb = (t * 2 + 1) * 9;
        uint32_t cnt[10];
        uint32_t c = 0, tt;
        #pragma unroll
        for (int i = 0; i < 9; ++i) {
            uint32_t a = s_cnt3[ba + i], bv = s_cnt3[bb + i];
            tt = a ^ bv; cnt[i] = tt ^ c; c = (a & bv) | (tt & c);
        }
        cnt[9] = c;
        // 632 = 0b1001111000 : bits 3,4,5,6,9 set
        uint32_t cy;
        cy = cnt[3];
        cy = cnt[4] | cy;
        cy = cnt[5] | cy;
        cy = cnt[6] | cy;
        cy = cnt[7] & cy;
        cy = cnt[8] & cy;
        cy = cnt[9] | cy;
        s_cnt4_enc[t] = ~cy;                  // enc bit = 1 -> +1
    }
    __syncthreads();

    // --- logits: 500 threads x 2 dims, +-W accumulate, shuffle reduce
    float partial[NCLS];
    #pragma unroll
    for (int cc = 0; cc < NCLS; ++cc) partial[cc] = 0.f;

    if (t < 500) {
        int d0 = 2 * t;
        uint32_t ew = s_cnt4_enc[d0 >> 5];
        float e0 = ((ew >> (d0 & 31)) & 1u) ? 1.0f : -1.0f;
        float e1 = ((ew >> ((d0 + 1) & 31)) & 1u) ? 1.0f : -1.0f;  // d0,d0+1 same word (d0 even)
        #pragma unroll
        for (int cc = 0; cc < NCLS; ++cc) {
            const float2* wv = (const float2*)(W + cc * DIMS + d0);
            float2 wl = *wv;
            partial[cc] = e0 * wl.x + e1 * wl.y;
        }
    }
    #pragma unroll
    for (int cc = 0; cc < NCLS; ++cc) {
        #pragma unroll
        for (int off = 32; off > 0; off >>= 1)
            partial[cc] += __shfl_down(partial[cc], off);
    }
    const int lane = t & 63, wid = t >> 6;
    if (lane == 0) {
        #pragma unroll
        for (int cc = 0; cc < NCLS; ++cc) s_red[wid][cc] = partial[cc];
    }
    __syncthreads();
    if (t < NCLS) {
        float acc = 0.f;
        #pragma unroll
        for (int v = 0; v < 8; ++v) acc += s_red[v][t];
        out[b * NCLS + t] = acc;
    }
}

extern "C" void kernel_launch(void* const* d_in, const int* in_sizes, int n_in,
                              void* d_out, int out_size, void* d_ws, size_t ws_size,
                              hipStream_t stream) {
    const float* x        = (const float*)d_in[0];  // [256,28,28]
    const float* position = (const float*)d_in[1];  // [784,1000]
    const float* vtab     = (const float*)d_in[2];  // [10,1000]
    const float* W        = (const float*)d_in[3];  // [10,1000]
    float* out            = (float*)d_out;          // [256,10]

    pack_ballot<<<200, 256, 0, stream>>>(position, vtab, (uint64_t*)d_ws);
    hdc_main<<<NBATCH, 512, 0, stream>>>(x, W, (const uint32_t*)d_ws, out);
}